// Round 1
// baseline (2053.139 us; speedup 1.0000x reference)
//
#include <hip/hip_runtime.h>
#include <cstdint>

#define HW_ 4096

// ---------------- depthwise 3x3, pad 1 (C=256, H=W=64) ----------------
__global__ __launch_bounds__(256) void dwconv_kernel(
    const float* __restrict__ x, const float* __restrict__ w,
    float* __restrict__ y) {
  int idx = blockIdx.x * 256 + threadIdx.x;
  int p  = idx & 4095;
  int c  = (idx >> 12) & 255;
  int ix = p & 63, iy = p >> 6;
  const float* wp = w + c * 9;
  const float* xp = x + (size_t)(idx - p);  // start of this channel plane
  float acc = 0.f;
#pragma unroll
  for (int dy = -1; dy <= 1; ++dy) {
    int yy = iy + dy;
    if (yy < 0 || yy > 63) continue;
#pragma unroll
    for (int dx = -1; dx <= 1; ++dx) {
      int xx = ix + dx;
      if (xx < 0 || xx > 63) continue;
      acc += xp[yy * 64 + xx] * wp[(dy + 1) * 3 + (dx + 1)];
    }
  }
  y[idx] = acc;
}

// ---------------- pointwise conv = GEMM [OC,IC] x [IC,HW] ----------------
// tile: 64 oc x 128 p, block 256 threads, each thread 8 oc x 4 p
__global__ __launch_bounds__(256) void pwconv_kernel(
    const float* __restrict__ x, const float* __restrict__ w,
    float* __restrict__ y, int IC, int OC) {
  __shared__ float xs[64][128];  // 32 KB
  __shared__ float ws[64][64];   // 16 KB
  int b   = blockIdx.z;
  int oc0 = blockIdx.y * 64;
  int p0  = blockIdx.x * 128;
  int tid = threadIdx.x;
  int tp  = tid & 31;       // p-group (4 consecutive p each)
  int toc = tid >> 5;       // 0..7 (8 oc each)
  float acc[8][4] = {};
  const float* xb = x + (size_t)b * IC * HW_ + p0;
  for (int ic0 = 0; ic0 < IC; ic0 += 64) {
#pragma unroll
    for (int k = 0; k < 8; ++k) {          // 64x128 floats, 8 float4/thread
      int f = tid + k * 256;
      int ic = f >> 5, p4 = f & 31;
      *(float4*)&xs[ic][p4 * 4] =
          *(const float4*)(xb + (size_t)(ic0 + ic) * HW_ + p4 * 4);
    }
#pragma unroll
    for (int k = 0; k < 4; ++k) {          // 64x64 floats, 4 float4/thread
      int f = tid + k * 256;
      int oc = f >> 4, icq = f & 15;
      *(float4*)&ws[oc][icq * 4] =
          *(const float4*)(w + (size_t)(oc0 + oc) * IC + ic0 + icq * 4);
    }
    __syncthreads();
#pragma unroll
    for (int ic4 = 0; ic4 < 16; ++ic4) {
      float4 xv0 = *(const float4*)&xs[ic4 * 4 + 0][tp * 4];
      float4 xv1 = *(const float4*)&xs[ic4 * 4 + 1][tp * 4];
      float4 xv2 = *(const float4*)&xs[ic4 * 4 + 2][tp * 4];
      float4 xv3 = *(const float4*)&xs[ic4 * 4 + 3][tp * 4];
#pragma unroll
      for (int oo = 0; oo < 8; ++oo) {
        float4 wv = *(const float4*)&ws[toc * 8 + oo][ic4 * 4];
        acc[oo][0] += wv.x * xv0.x + wv.y * xv1.x + wv.z * xv2.x + wv.w * xv3.x;
        acc[oo][1] += wv.x * xv0.y + wv.y * xv1.y + wv.z * xv2.y + wv.w * xv3.y;
        acc[oo][2] += wv.x * xv0.z + wv.y * xv1.z + wv.z * xv2.z + wv.w * xv3.z;
        acc[oo][3] += wv.x * xv0.w + wv.y * xv1.w + wv.z * xv2.w + wv.w * xv3.w;
      }
    }
    __syncthreads();
  }
#pragma unroll
  for (int oo = 0; oo < 8; ++oo) {
    float4 o = {acc[oo][0], acc[oo][1], acc[oo][2], acc[oo][3]};
    *(float4*)(y + ((size_t)b * OC + oc0 + toc * 8 + oo) * HW_ + p0 + tp * 4) = o;
  }
}

// ---------------- bilinear 64x64 -> 16x16 align_corners for k and v ----------------
__global__ __launch_bounds__(256) void bilinear_kernel(
    const float* __restrict__ qkv, float* __restrict__ ks, float* __restrict__ vs) {
  int idx = blockIdx.x * 256 + threadIdx.x;   // 2*8*256*256 = 1,048,576
  int ox = idx & 15, oy = (idx >> 4) & 15;
  int c = (idx >> 8) & 255;
  int b = (idx >> 16) & 7;
  int which = idx >> 19;   // 0 = k (ch 256..511), 1 = v (ch 512..767)
  const float* src = qkv + ((size_t)b * 768 + (which ? 512 : 256) + c) * HW_;
  const float s = 63.0f / 15.0f;
  float ys = oy * s, xf = ox * s;
  int y0 = (int)ys, x0 = (int)xf;             // >=0 so trunc == floor
  int y1 = min(y0 + 1, 63), x1 = min(x0 + 1, 63);
  float wy = ys - (float)y0, wx = xf - (float)x0;
  float v00 = src[y0 * 64 + x0], v01 = src[y0 * 64 + x1];
  float v10 = src[y1 * 64 + x0], v11 = src[y1 * 64 + x1];
  float top = v00 * (1.f - wx) + v01 * wx;
  float bot = v10 * (1.f - wx) + v11 * wx;
  float val = top * (1.f - wy) + bot * wy;
  (which ? vs : ks)[((size_t)b * 256 + c) * 256 + oy * 16 + ox] = val;
}

// ---------------- q: gather heads + LayerNorm -> [B,8,4096,32] ----------------
__global__ __launch_bounds__(256) void qln_kernel(
    const float* __restrict__ qkv, const float* __restrict__ g,
    const float* __restrict__ bb, float* __restrict__ qln) {
  int idx = blockIdx.x * 256 + threadIdx.x;   // (b*8+h)*4096 + i
  int i = idx & 4095;
  int bh = idx >> 12;
  int h = bh & 7, b = bh >> 3;
  const float* base = qkv + ((size_t)b * 768 + h) * HW_ + i;  // channel d*8+h
  float v[32];
  float mu = 0.f;
#pragma unroll
  for (int d = 0; d < 32; ++d) { v[d] = base[(size_t)d * 8 * HW_]; mu += v[d]; }
  mu *= (1.f / 32.f);
  float var = 0.f;
#pragma unroll
  for (int d = 0; d < 32; ++d) { float t = v[d] - mu; var += t * t; }
  var *= (1.f / 32.f);
  float inv = 1.0f / sqrtf(var + 1e-6f);
  float* o = qln + (size_t)idx * 32;
#pragma unroll
  for (int d4 = 0; d4 < 8; ++d4) {
    float4 r;
    r.x = (v[d4*4+0] - mu) * inv * g[h*32 + d4*4+0] + bb[h*32 + d4*4+0];
    r.y = (v[d4*4+1] - mu) * inv * g[h*32 + d4*4+1] + bb[h*32 + d4*4+1];
    r.z = (v[d4*4+2] - mu) * inv * g[h*32 + d4*4+2] + bb[h*32 + d4*4+2];
    r.w = (v[d4*4+3] - mu) * inv * g[h*32 + d4*4+3] + bb[h*32 + d4*4+3];
    *(float4*)(o + d4 * 4) = r;
  }
}

// ---------------- k: heads + LN -> [B,8,256,32]; v: heads -> [B,8,256,32] ----------------
__global__ __launch_bounds__(256) void kvln_kernel(
    const float* __restrict__ ksr, const float* __restrict__ vsr,
    const float* __restrict__ g, const float* __restrict__ bb,
    float* __restrict__ kln, float* __restrict__ vt) {
  int idx = blockIdx.x * 256 + threadIdx.x;   // (b*8+h)*256 + j
  int j = idx & 255;
  int bh = idx >> 8;
  int h = bh & 7, b = bh >> 3;
  const float* kb = ksr + ((size_t)b * 256 + h) * 256 + j;   // channel d*8+h -> +d*2048
  const float* vb = vsr + ((size_t)b * 256 + h) * 256 + j;
  float v[32];
  float mu = 0.f;
#pragma unroll
  for (int d = 0; d < 32; ++d) { v[d] = kb[d * 2048]; mu += v[d]; }
  mu *= (1.f / 32.f);
  float var = 0.f;
#pragma unroll
  for (int d = 0; d < 32; ++d) { float t = v[d] - mu; var += t * t; }
  var *= (1.f / 32.f);
  float inv = 1.0f / sqrtf(var + 1e-6f);
  float* ko = kln + (size_t)idx * 32;
  float* vo = vt + (size_t)idx * 32;
#pragma unroll
  for (int d = 0; d < 32; ++d)
    ko[d] = (v[d] - mu) * inv * g[h * 32 + d] + bb[h * 32 + d];
#pragma unroll
  for (int d = 0; d < 32; ++d) vo[d] = vb[d * 2048];
}

// ---------------- attention: attn=(qk^T+bias)/32 (written out) ; out=attn*v ----------------
// block = one (b,h,32 q-rows). LDS: attn tile only. q in regs, k/v via L1.
__global__ __launch_bounds__(256) void attn_kernel(
    const float* __restrict__ qln, const float* __restrict__ kln,
    const float* __restrict__ vt, const float* __restrict__ btab,
    const int* __restrict__ relidx, float* __restrict__ attn_out,
    float* __restrict__ out_nchw) {
  __shared__ float attn_s[32][260];   // padded: rows land on different banks
  int tile = blockIdx.x, h = blockIdx.y, b = blockIdx.z;
  int bh = b * 8 + h;
  int i0 = tile * 32;
  int tid = threadIdx.x;
  int i_local = tid >> 3, t8 = tid & 7;
  int i = i0 + i_local;
  int iy = i >> 6, ix = i & 63;
  const int* relrow = relidx + ((iy >> 2) * 16 + (ix >> 2)) * 256;

  // q row into registers (8 float4). 8-way same-address across t8 -> L1 broadcast.
  const float4* q4 = (const float4*)(qln + ((size_t)bh * 4096 + i) * 32);
  float4 qv[8];
#pragma unroll
  for (int d4 = 0; d4 < 8; ++d4) qv[d4] = q4[d4];

  const float4* kb4 = (const float4*)(kln + (size_t)bh * 256 * 32);
  for (int jj = 0; jj < 32; ++jj) {
    int j = jj * 8 + t8;
    const float4* kj = kb4 + j * 8;
    float acc = 0.f;
#pragma unroll
    for (int d4 = 0; d4 < 8; ++d4) {
      float4 kq = kj[d4];
      acc += qv[d4].x * kq.x + qv[d4].y * kq.y + qv[d4].z * kq.z + qv[d4].w * kq.w;
    }
    float bias = btab[relrow[j] * 8 + h];
    attn_s[i_local][j] = (acc + bias) * 0.03125f;
  }
  __syncthreads();

  // coalesced attn tile store: 32 x 256 floats
  {
    float* abase = attn_out + ((size_t)bh * 4096 + i0) * 256;
#pragma unroll
    for (int k = 0; k < 8; ++k) {
      int f = tid + k * 256;          // 2048 float4s
      int row = f >> 6, c4 = f & 63;
      *(float4*)(abase + (size_t)row * 256 + c4 * 4) =
          *(const float4*)&attn_s[row][c4 * 4];
    }
  }

  // out[i, d] = sum_j attn[i,j] * v[j,d]; thread owns d = t8*4..t8*4+3
  const float4* vb4 = (const float4*)(vt + (size_t)bh * 256 * 32);
  float4 acc4 = {0.f, 0.f, 0.f, 0.f};
  for (int j = 0; j < 256; ++j) {
    float a = attn_s[i_local][j];
    float4 vv = vb4[j * 8 + t8];
    acc4.x += a * vv.x; acc4.y += a * vv.y; acc4.z += a * vv.z; acc4.w += a * vv.w;
  }
  int d0 = t8 * 4;
  float av[4] = {acc4.x, acc4.y, acc4.z, acc4.w};
#pragma unroll
  for (int dd = 0; dd < 4; ++dd) {
    int c = (d0 + dd) * 8 + h;       // NCHW channel = d*8 + h
    out_nchw[((size_t)b * 256 + c) * HW_ + i] = av[dd];
  }
}

extern "C" void kernel_launch(void* const* d_in, const int* in_sizes, int n_in,
                              void* d_out, int out_size, void* d_ws, size_t ws_size,
                              hipStream_t stream) {
  const float* x      = (const float*)d_in[0];
  const float* qkv_dw = (const float*)d_in[1];
  const float* qkv_pw = (const float*)d_in[2];
  const float* out_dw = (const float*)d_in[3];
  const float* out_pw = (const float*)d_in[4];
  const float* gq     = (const float*)d_in[5];
  const float* bq     = (const float*)d_in[6];
  const float* gk     = (const float*)d_in[7];
  const float* bk     = (const float*)d_in[8];
  const float* btab   = (const float*)d_in[9];
  const int*   relidx = (const int*)d_in[10];

  float* out  = (float*)d_out;            // 8,388,608 floats
  float* attn = out + 8388608;            // 67,108,864 floats

  float* ws   = (float*)d_ws;
  float* bufA = ws;                       // 8,388,608   dw1 out, later out_nchw
  float* qkv  = ws + 8388608;             // 25,165,824  qkv, later dw2 out
  float* ksr  = ws + 33554432;            // 524,288
  float* vsr  = ksr + 524288;             // 524,288
  float* kln  = ksr + 1048576;            // 524,288
  float* vt   = ksr + 1572864;            // 524,288
  float* qln  = out;                      // alias: out region dead until final pwconv
  float* dw2  = qkv;                      // alias: qkv region dead after qln_kernel

  dwconv_kernel<<<32768, 256, 0, stream>>>(x, qkv_dw, bufA);
  pwconv_kernel<<<dim3(32, 12, 8), 256, 0, stream>>>(bufA, qkv_pw, qkv, 256, 768);
  bilinear_kernel<<<4096, 256, 0, stream>>>(qkv, ksr, vsr);
  qln_kernel<<<1024, 256, 0, stream>>>(qkv, gq, bq, qln);
  kvln_kernel<<<64, 256, 0, stream>>>(ksr, vsr, gk, bk, kln, vt);
  attn_kernel<<<dim3(128, 8, 8), 256, 0, stream>>>(qln, kln, vt, btab, relidx,
                                                   attn, bufA);
  dwconv_kernel<<<32768, 256, 0, stream>>>(bufA, out_dw, dw2);
  pwconv_kernel<<<dim3(32, 4, 8), 256, 0, stream>>>(dw2, out_pw, out, 256, 256);
}

// Round 2
// 942.847 us; speedup vs baseline: 2.1776x; 2.1776x over previous
//
#include <hip/hip_runtime.h>
#include <cstdint>

#define HW_ 4096

typedef __attribute__((ext_vector_type(8))) short bf16x8;
typedef __attribute__((ext_vector_type(4))) short bf16x4;
typedef __attribute__((ext_vector_type(4))) float f32x4;

static __device__ inline unsigned short f2bf(float f) {
  unsigned u = __builtin_bit_cast(unsigned, f);
  u += 0x7FFF + ((u >> 16) & 1);
  return (unsigned short)(u >> 16);
}

// ---------------- depthwise 3x3, pad 1 (C=256, H=W=64) ----------------
__global__ __launch_bounds__(256) void dwconv_kernel(
    const float* __restrict__ x, const float* __restrict__ w,
    float* __restrict__ y) {
  int idx = blockIdx.x * 256 + threadIdx.x;
  int p  = idx & 4095;
  int c  = (idx >> 12) & 255;
  int ix = p & 63, iy = p >> 6;
  const float* wp = w + c * 9;
  const float* xp = x + (size_t)(idx - p);
  float acc = 0.f;
#pragma unroll
  for (int dy = -1; dy <= 1; ++dy) {
    int yy = iy + dy;
    if (yy < 0 || yy > 63) continue;
#pragma unroll
    for (int dx = -1; dx <= 1; ++dx) {
      int xx = ix + dx;
      if (xx < 0 || xx > 63) continue;
      acc += xp[yy * 64 + xx] * wp[(dy + 1) * 3 + (dx + 1)];
    }
  }
  y[idx] = acc;
}

// ---------------- pointwise conv = GEMM [OC,IC] x [IC,HW] ----------------
__global__ __launch_bounds__(256) void pwconv_kernel(
    const float* __restrict__ x, const float* __restrict__ w,
    float* __restrict__ y, int IC, int OC) {
  __shared__ float xs[64][128];
  __shared__ float ws[64][64];
  int b   = blockIdx.z;
  int oc0 = blockIdx.y * 64;
  int p0  = blockIdx.x * 128;
  int tid = threadIdx.x;
  int tp  = tid & 31;
  int toc = tid >> 5;
  float acc[8][4] = {};
  const float* xb = x + (size_t)b * IC * HW_ + p0;
  for (int ic0 = 0; ic0 < IC; ic0 += 64) {
#pragma unroll
    for (int k = 0; k < 8; ++k) {
      int f = tid + k * 256;
      int ic = f >> 5, p4 = f & 31;
      *(float4*)&xs[ic][p4 * 4] =
          *(const float4*)(xb + (size_t)(ic0 + ic) * HW_ + p4 * 4);
    }
#pragma unroll
    for (int k = 0; k < 4; ++k) {
      int f = tid + k * 256;
      int oc = f >> 4, icq = f & 15;
      *(float4*)&ws[oc][icq * 4] =
          *(const float4*)(w + (size_t)(oc0 + oc) * IC + ic0 + icq * 4);
    }
    __syncthreads();
#pragma unroll
    for (int ic4 = 0; ic4 < 16; ++ic4) {
      float4 xv0 = *(const float4*)&xs[ic4 * 4 + 0][tp * 4];
      float4 xv1 = *(const float4*)&xs[ic4 * 4 + 1][tp * 4];
      float4 xv2 = *(const float4*)&xs[ic4 * 4 + 2][tp * 4];
      float4 xv3 = *(const float4*)&xs[ic4 * 4 + 3][tp * 4];
#pragma unroll
      for (int oo = 0; oo < 8; ++oo) {
        float4 wv = *(const float4*)&ws[toc * 8 + oo][ic4 * 4];
        acc[oo][0] += wv.x * xv0.x + wv.y * xv1.x + wv.z * xv2.x + wv.w * xv3.x;
        acc[oo][1] += wv.x * xv0.y + wv.y * xv1.y + wv.z * xv2.y + wv.w * xv3.y;
        acc[oo][2] += wv.x * xv0.z + wv.y * xv1.z + wv.z * xv2.z + wv.w * xv3.z;
        acc[oo][3] += wv.x * xv0.w + wv.y * xv1.w + wv.z * xv2.w + wv.w * xv3.w;
      }
    }
    __syncthreads();
  }
#pragma unroll
  for (int oo = 0; oo < 8; ++oo) {
    float4 o = {acc[oo][0], acc[oo][1], acc[oo][2], acc[oo][3]};
    *(float4*)(y + ((size_t)b * OC + oc0 + toc * 8 + oo) * HW_ + p0 + tp * 4) = o;
  }
}

// ---------------- bilinear 64x64 -> 16x16 align_corners for k and v ----------------
__global__ __launch_bounds__(256) void bilinear_kernel(
    const float* __restrict__ qkv, float* __restrict__ ks, float* __restrict__ vs) {
  int idx = blockIdx.x * 256 + threadIdx.x;   // 2^20
  int ox = idx & 15, oy = (idx >> 4) & 15;
  int c = (idx >> 8) & 255;
  int b = (idx >> 16) & 7;
  int which = idx >> 19;
  const float* src = qkv + ((size_t)b * 768 + (which ? 512 : 256) + c) * HW_;
  const float s = 63.0f / 15.0f;
  float ys = oy * s, xf = ox * s;
  int y0 = (int)ys, x0 = (int)xf;
  int y1 = min(y0 + 1, 63), x1 = min(x0 + 1, 63);
  float wy = ys - (float)y0, wx = xf - (float)x0;
  float v00 = src[y0 * 64 + x0], v01 = src[y0 * 64 + x1];
  float v10 = src[y1 * 64 + x0], v11 = src[y1 * 64 + x1];
  float top = v00 * (1.f - wx) + v01 * wx;
  float bot = v10 * (1.f - wx) + v11 * wx;
  float val = top * (1.f - wy) + bot * wy;
  (which ? vs : ks)[((size_t)b * 256 + c) * 256 + oy * 16 + ox] = val;
}

// ---------------- q: gather heads + LayerNorm -> bf16 [B,8,4096,32] ----------------
__global__ __launch_bounds__(256) void qln_kernel(
    const float* __restrict__ qkv, const float* __restrict__ g,
    const float* __restrict__ bb, unsigned short* __restrict__ qout) {
  int idx = blockIdx.x * 256 + threadIdx.x;   // (b*8+h)*4096 + i
  int i = idx & 4095;
  int bh = idx >> 12;
  int h = bh & 7, b = bh >> 3;
  const float* base = qkv + ((size_t)b * 768 + h) * HW_ + i;
  float v[32];
  float mu = 0.f;
#pragma unroll
  for (int d = 0; d < 32; ++d) { v[d] = base[(size_t)d * 8 * HW_]; mu += v[d]; }
  mu *= (1.f / 32.f);
  float var = 0.f;
#pragma unroll
  for (int d = 0; d < 32; ++d) { float t = v[d] - mu; var += t * t; }
  var *= (1.f / 32.f);
  float inv = 1.0f / sqrtf(var + 1e-6f);
  unsigned r[16];
#pragma unroll
  for (int t = 0; t < 16; ++t) {
    float y0 = (v[2*t]   - mu) * inv * g[h*32 + 2*t]   + bb[h*32 + 2*t];
    float y1 = (v[2*t+1] - mu) * inv * g[h*32 + 2*t+1] + bb[h*32 + 2*t+1];
    r[t] = (unsigned)f2bf(y0) | ((unsigned)f2bf(y1) << 16);
  }
  unsigned short* o = qout + (size_t)idx * 32;
#pragma unroll
  for (int t4 = 0; t4 < 4; ++t4) {
    uint4 pk = {r[t4*4], r[t4*4+1], r[t4*4+2], r[t4*4+3]};
    *(uint4*)(o + t4 * 8) = pk;
  }
}

// ---------------- k: heads + LN -> bf16 [bh,256,32]; v -> bf16 fragment layout ---------
__global__ __launch_bounds__(256) void kvln_kernel(
    const float* __restrict__ ksr, const float* __restrict__ vsr,
    const float* __restrict__ g, const float* __restrict__ bb,
    unsigned short* __restrict__ kln, unsigned short* __restrict__ vfrag) {
  int idx = blockIdx.x * 256 + threadIdx.x;   // (b*8+h)*256 + j
  int j = idx & 255;
  int bh = idx >> 8;
  int h = bh & 7, b = bh >> 3;
  const float* kb = ksr + ((size_t)b * 256 + h) * 256 + j;   // channel d*8+h
  const float* vb = vsr + ((size_t)b * 256 + h) * 256 + j;
  float v[32];
  float mu = 0.f;
#pragma unroll
  for (int d = 0; d < 32; ++d) { v[d] = kb[d * 2048]; mu += v[d]; }
  mu *= (1.f / 32.f);
  float var = 0.f;
#pragma unroll
  for (int d = 0; d < 32; ++d) { float t = v[d] - mu; var += t * t; }
  var *= (1.f / 32.f);
  float inv = 1.0f / sqrtf(var + 1e-6f);
  unsigned r[16];
#pragma unroll
  for (int t = 0; t < 16; ++t) {
    float y0 = (v[2*t]   - mu) * inv * g[h*32 + 2*t]   + bb[h*32 + 2*t];
    float y1 = (v[2*t+1] - mu) * inv * g[h*32 + 2*t+1] + bb[h*32 + 2*t+1];
    r[t] = (unsigned)f2bf(y0) | ((unsigned)f2bf(y1) << 16);
  }
  unsigned short* ko = kln + (size_t)idx * 32;
#pragma unroll
  for (int t4 = 0; t4 < 4; ++t4) {
    uint4 pk = {r[t4*4], r[t4*4+1], r[t4*4+2], r[t4*4+3]};
    *(uint4*)(ko + t4 * 8) = pk;
  }
  // V in 16x16x16 A-fragment layout: elem (j,d) -> [bh*32 + (j>>4)*2 + (d>>4)]*256
  //                                              + ((j>>2)&3)*64 + (d&15)*4 + (j&3)
  int c = j >> 4, gq = (j >> 2) & 3, ii = j & 3;
  unsigned short* vo = vfrag + (size_t)bh * 32 * 256;
#pragma unroll
  for (int d = 0; d < 32; ++d) {
    int dt = d >> 4, dr = d & 15;
    vo[(c * 2 + dt) * 256 + (gq * 16 + dr) * 4 + ii] = f2bf(vb[d * 2048]);
  }
}

// ---------------- bias_pre[h][g][j] = btab[relidx[g*256+j]*8+h] / 32 ----------------
__global__ __launch_bounds__(256) void biaspre_kernel(
    const float* __restrict__ btab, const int* __restrict__ relidx,
    float* __restrict__ bias_pre) {
  int idx = blockIdx.x * 256 + threadIdx.x;   // h*65536 + g*256 + j
  int j = idx & 255, g = (idx >> 8) & 255, h = idx >> 16;
  bias_pre[idx] = btab[relidx[g * 256 + j] * 8 + h] * 0.03125f;
}

// ---------------- MFMA attention ----------------
// block = 256 thr (4 waves), each wave owns 16 q-rows. grid (64,8,8).
// swapped QK^T: S' = mfma(Kfrag, Qfrag) -> lane holds attn[q=l&15][j=c*16+(l>>4)*4+r]
// PV swapped: out^T = mfma(V^Tfrag, attn_bf16)
__global__ __launch_bounds__(256) void attn_mfma_kernel(
    const unsigned short* __restrict__ qln, const unsigned short* __restrict__ kln,
    const unsigned short* __restrict__ vfrag, const float* __restrict__ bias_pre,
    float* __restrict__ attn_out, float* __restrict__ out_nchw) {
  int tile = blockIdx.x, h = blockIdx.y, b = blockIdx.z;
  int bh = b * 8 + h;
  int tid = threadIdx.x;
  int w = tid >> 6, l = tid & 63;
  int lr = l & 15, lg = l >> 4;
  int qbase = tile * 64 + w * 16;
  int q = qbase + lr;
  int iy = q >> 6, ix = q & 63;
  int g = (iy >> 2) * 16 + (ix >> 2);

  bf16x8 qf = *(const bf16x8*)(qln + ((size_t)bh * 4096 + q) * 32 + lg * 8);

  const unsigned short* kbase = kln + (size_t)bh * 256 * 32 + lr * 32 + lg * 8;
  const unsigned short* vbase = vfrag + (size_t)bh * 32 * 256 + l * 4;
  const float* bbase = bias_pre + ((size_t)h * 256 + g) * 256 + lg * 4;
  float* abase = attn_out + ((size_t)bh * 4096 + q) * 256 + lg * 4;

  f32x4 z = {0.f, 0.f, 0.f, 0.f};
  f32x4 oacc0 = z, oacc1 = z;
#pragma unroll
  for (int c = 0; c < 16; ++c) {
    bf16x8 kf = *(const bf16x8*)(kbase + c * 16 * 32);
    f32x4 s = __builtin_amdgcn_mfma_f32_16x16x32_bf16(kf, qf, z, 0, 0, 0);
    f32x4 bias = *(const f32x4*)(bbase + c * 16);
    f32x4 t = s * 0.03125f + bias;
    *(f32x4*)(abase + c * 16) = t;
    bf16x4 pb;
    pb[0] = (short)f2bf(t.x);
    pb[1] = (short)f2bf(t.y);
    pb[2] = (short)f2bf(t.z);
    pb[3] = (short)f2bf(t.w);
    bf16x4 va0 = *(const bf16x4*)(vbase + (c * 2 + 0) * 256);
    bf16x4 va1 = *(const bf16x4*)(vbase + (c * 2 + 1) * 256);
    oacc0 = __builtin_amdgcn_mfma_f32_16x16x16bf16_1k(va0, pb, oacc0, 0, 0, 0);
    oacc1 = __builtin_amdgcn_mfma_f32_16x16x16bf16_1k(va1, pb, oacc1, 0, 0, 0);
  }
  // lane holds out[q' = qbase+lr][d = dt*16 + lg*4 + r]
  float ov[8] = {oacc0.x, oacc0.y, oacc0.z, oacc0.w,
                 oacc1.x, oacc1.y, oacc1.z, oacc1.w};
#pragma unroll
  for (int dt = 0; dt < 2; ++dt) {
#pragma unroll
    for (int r = 0; r < 4; ++r) {
      int d = dt * 16 + lg * 4 + r;
      int cc = d * 8 + h;
      out_nchw[((size_t)b * 256 + cc) * HW_ + qbase + lr] = ov[dt * 4 + r];
    }
  }
}

extern "C" void kernel_launch(void* const* d_in, const int* in_sizes, int n_in,
                              void* d_out, int out_size, void* d_ws, size_t ws_size,
                              hipStream_t stream) {
  const float* x      = (const float*)d_in[0];
  const float* qkv_dw = (const float*)d_in[1];
  const float* qkv_pw = (const float*)d_in[2];
  const float* out_dw = (const float*)d_in[3];
  const float* out_pw = (const float*)d_in[4];
  const float* gq     = (const float*)d_in[5];
  const float* bq     = (const float*)d_in[6];
  const float* gk     = (const float*)d_in[7];
  const float* bk     = (const float*)d_in[8];
  const float* btab   = (const float*)d_in[9];
  const int*   relidx = (const int*)d_in[10];

  float* out  = (float*)d_out;            // 8,388,608 floats
  float* attn = out + 8388608;            // 67,108,864 floats

  float* ws       = (float*)d_ws;
  float* bufA     = ws;                       // 8,388,608  dw1 out, later attn spatial out
  float* qkv      = ws + 8388608;             // 25,165,824 qkv, later dw2 out
  float* ksr      = ws + 33554432;            // 524,288
  float* vsr      = ws + 34078720;            // 524,288
  float* bias_pre = ws + 34603008;            // 524,288
  unsigned short* kln   = (unsigned short*)(ws + 35127296);  // 524,288 bf16
  unsigned short* vfrag = (unsigned short*)(ws + 35389440);  // 524,288 bf16
  unsigned short* qlnb  = (unsigned short*)out;  // alias: out dead until pwconv2 (16.8MB<=33.5MB)
  float* dw2 = qkv;

  dwconv_kernel<<<32768, 256, 0, stream>>>(x, qkv_dw, bufA);
  pwconv_kernel<<<dim3(32, 12, 8), 256, 0, stream>>>(bufA, qkv_pw, qkv, 256, 768);
  bilinear_kernel<<<4096, 256, 0, stream>>>(qkv, ksr, vsr);
  qln_kernel<<<1024, 256, 0, stream>>>(qkv, gq, bq, qlnb);
  kvln_kernel<<<64, 256, 0, stream>>>(ksr, vsr, gk, bk, kln, vfrag);
  biaspre_kernel<<<2048, 256, 0, stream>>>(btab, relidx, bias_pre);
  attn_mfma_kernel<<<dim3(64, 8, 8), 256, 0, stream>>>(qlnb, kln, vfrag, bias_pre,
                                                       attn, bufA);
  dwconv_kernel<<<32768, 256, 0, stream>>>(bufA, out_dw, dw2);
  pwconv_kernel<<<dim3(32, 4, 8), 256, 0, stream>>>(dw2, out_pw, out, 256, 256);
}

// Round 3
// 248.971 us; speedup vs baseline: 8.2465x; 3.7870x over previous
//
#include <hip/hip_runtime.h>
#include <cstdint>

#define HW_ 4096

typedef __attribute__((ext_vector_type(8))) short bf16x8;
typedef __attribute__((ext_vector_type(4))) short bf16x4;
typedef __attribute__((ext_vector_type(4))) float f32x4;

static __device__ __forceinline__ unsigned short f2bf(float f) {
  unsigned u = __builtin_bit_cast(unsigned, f);
  u += 0x7FFF + ((u >> 16) & 1);
  return (unsigned short)(u >> 16);
}

static __device__ __forceinline__ void gl_lds16(const unsigned short* g,
                                                unsigned short* s) {
  __builtin_amdgcn_global_load_lds(
      (const __attribute__((address_space(1))) unsigned int*)g,
      (__attribute__((address_space(3))) unsigned int*)s, 16, 0, 0);
}

// ---------- fused depthwise 3x3 (pad1) + bf16 + transpose -> XT[b][p][c] ----------
// block: 64 px (one spatial row) x 64 c. grid (64 iy, 4 cgrp, 8 b)
__global__ __launch_bounds__(256) void dwconv_t_kernel(
    const float* __restrict__ x, const float* __restrict__ w9,
    unsigned short* __restrict__ xT) {
  __shared__ unsigned short lds_t[64][66];
  int iy = blockIdx.x;
  int cg = blockIdx.y;
  int b  = blockIdx.z;
  int tid = threadIdx.x;
  int px  = tid & 63;
  int cl0 = (tid >> 6) * 16;
  for (int e = 0; e < 16; ++e) {
    int c = cg * 64 + cl0 + e;
    const float* xp = x + ((size_t)b * 256 + c) * HW_;
    const float* wp = w9 + c * 9;
    float acc = 0.f;
#pragma unroll
    for (int dy = -1; dy <= 1; ++dy) {
      int yy = iy + dy;
      if (yy < 0 || yy > 63) continue;
#pragma unroll
      for (int dx = -1; dx <= 1; ++dx) {
        int xx = px + dx;
        if (xx < 0 || xx > 63) continue;
        acc += xp[yy * 64 + xx] * wp[(dy + 1) * 3 + dx + 1];
      }
    }
    lds_t[cl0 + e][px] = f2bf(acc);
  }
  __syncthreads();
#pragma unroll
  for (int j = 0; j < 2; ++j) {
    int flat = tid + j * 256;
    int rpx = flat >> 3, cseg = flat & 7;
    unsigned v0 = (unsigned)lds_t[cseg*8+0][rpx] | ((unsigned)lds_t[cseg*8+1][rpx] << 16);
    unsigned v1 = (unsigned)lds_t[cseg*8+2][rpx] | ((unsigned)lds_t[cseg*8+3][rpx] << 16);
    unsigned v2 = (unsigned)lds_t[cseg*8+4][rpx] | ((unsigned)lds_t[cseg*8+5][rpx] << 16);
    unsigned v3 = (unsigned)lds_t[cseg*8+6][rpx] | ((unsigned)lds_t[cseg*8+7][rpx] << 16);
    uint4 pk = {v0, v1, v2, v3};
    *(uint4*)(xT + ((size_t)b * 4096 + iy * 64 + rpx) * 256 + cg * 64 + cseg * 8) = pk;
  }
}

// ---------- weights fp32 -> bf16 (qkv_pw 768x256 then out_pw 256x256) ----------
__global__ __launch_bounds__(256) void wcvt_kernel(
    const float* __restrict__ pw1, const float* __restrict__ pw2,
    unsigned short* __restrict__ wb) {
  int idx = blockIdx.x * 256 + threadIdx.x;   // 262144
  float v = idx < 196608 ? pw1[idx] : pw2[idx - 196608];
  wb[idx] = f2bf(v);
}

// ---------- pointwise conv as bf16 MFMA GEMM ----------
// Y[b][oc][p] = sum_ic W[oc][ic] * XT[b][p][ic].  128x128 tile, BK=64, 4 waves.
// LDS XOR-swizzle (16B units): physical(row,cu) holds logical(row, cu^(row&7));
// applied on the global source (stage) and on ds_read addresses (both-sides rule).
__global__ __launch_bounds__(256) void pwconv_mfma_kernel(
    const unsigned short* __restrict__ XT, const unsigned short* __restrict__ W,
    float* __restrict__ Y, int OC) {
  __shared__ unsigned short As[128 * 64];
  __shared__ unsigned short Bs[128 * 64];
  int b = blockIdx.z, oc0 = blockIdx.y * 128, p0 = blockIdx.x * 128;
  int tid = threadIdx.x;
  int w = tid >> 6, l = tid & 63;
  int wm = w >> 1, wn = w & 1;
  int lr = l & 15, lg = l >> 4;
  const unsigned short* Wp = W + (size_t)oc0 * 256;
  const unsigned short* Xp = XT + ((size_t)b * 4096 + p0) * 256;
  f32x4 acc[4][4] = {};
  for (int kt = 0; kt < 4; ++kt) {
    int k0 = kt * 64;
#pragma unroll
    for (int j = 0; j < 4; ++j) {
      int chunk = w * 4 + j;            // wave-uniform
      int row = chunk * 8 + (l >> 3);
      int lcu = (l & 7) ^ (row & 7);    // inverse-swizzled source column
      gl_lds16(Wp + (size_t)row * 256 + k0 + lcu * 8, &As[chunk * 512]);
      gl_lds16(Xp + (size_t)row * 256 + k0 + lcu * 8, &Bs[chunk * 512]);
    }
    __syncthreads();
#pragma unroll
    for (int ks = 0; ks < 2; ++ks) {
      bf16x8 af[4], bfr[4];
      int ku = ks * 4 + lg;
#pragma unroll
      for (int mi = 0; mi < 4; ++mi) {
        int row = wm * 64 + mi * 16 + lr;
        af[mi] = *(const bf16x8*)&As[row * 64 + (ku ^ (row & 7)) * 8];
      }
#pragma unroll
      for (int ni = 0; ni < 4; ++ni) {
        int row = wn * 64 + ni * 16 + lr;
        bfr[ni] = *(const bf16x8*)&Bs[row * 64 + (ku ^ (row & 7)) * 8];
      }
#pragma unroll
      for (int mi = 0; mi < 4; ++mi)
#pragma unroll
        for (int ni = 0; ni < 4; ++ni)
          acc[mi][ni] = __builtin_amdgcn_mfma_f32_16x16x32_bf16(
              af[mi], bfr[ni], acc[mi][ni], 0, 0, 0);
    }
    __syncthreads();
  }
  // D: col(l&15) = p-local (B rows), row((l>>4)*4+reg) = oc-local (A rows)
  float* Yb = Y + (size_t)b * OC * HW_;
#pragma unroll
  for (int mi = 0; mi < 4; ++mi)
#pragma unroll
    for (int ni = 0; ni < 4; ++ni)
#pragma unroll
      for (int r = 0; r < 4; ++r) {
        int oc = oc0 + wm * 64 + mi * 16 + lg * 4 + r;
        int p  = p0 + wn * 64 + ni * 16 + lr;
        Yb[(size_t)oc * HW_ + p] = acc[mi][ni][r];
      }
}

// ---------------- bilinear 64x64 -> 16x16 align_corners for k and v ----------------
__global__ __launch_bounds__(256) void bilinear_kernel(
    const float* __restrict__ qkv, float* __restrict__ ks, float* __restrict__ vs) {
  int idx = blockIdx.x * 256 + threadIdx.x;   // 2^20
  int ox = idx & 15, oy = (idx >> 4) & 15;
  int c = (idx >> 8) & 255;
  int b = (idx >> 16) & 7;
  int which = idx >> 19;
  const float* src = qkv + ((size_t)b * 768 + (which ? 512 : 256) + c) * HW_;
  const float s = 63.0f / 15.0f;
  float ys = oy * s, xf = ox * s;
  int y0 = (int)ys, x0 = (int)xf;
  int y1 = min(y0 + 1, 63), x1 = min(x0 + 1, 63);
  float wy = ys - (float)y0, wx = xf - (float)x0;
  float v00 = src[y0 * 64 + x0], v01 = src[y0 * 64 + x1];
  float v10 = src[y1 * 64 + x0], v11 = src[y1 * 64 + x1];
  float top = v00 * (1.f - wx) + v01 * wx;
  float bot = v10 * (1.f - wx) + v11 * wx;
  float val = top * (1.f - wy) + bot * wy;
  (which ? vs : ks)[((size_t)b * 256 + c) * 256 + oy * 16 + ox] = val;
}

// ---------------- q: gather heads + LayerNorm -> bf16 [B,8,4096,32] ----------------
__global__ __launch_bounds__(256) void qln_kernel(
    const float* __restrict__ qkv, const float* __restrict__ g,
    const float* __restrict__ bb, unsigned short* __restrict__ qout) {
  int idx = blockIdx.x * 256 + threadIdx.x;   // (b*8+h)*4096 + i
  int i = idx & 4095;
  int bh = idx >> 12;
  int h = bh & 7, b = bh >> 3;
  const float* base = qkv + ((size_t)b * 768 + h) * HW_ + i;
  float v[32];
  float mu = 0.f;
#pragma unroll
  for (int d = 0; d < 32; ++d) { v[d] = base[(size_t)d * 8 * HW_]; mu += v[d]; }
  mu *= (1.f / 32.f);
  float var = 0.f;
#pragma unroll
  for (int d = 0; d < 32; ++d) { float t = v[d] - mu; var += t * t; }
  var *= (1.f / 32.f);
  float inv = 1.0f / sqrtf(var + 1e-6f);
  unsigned r[16];
#pragma unroll
  for (int t = 0; t < 16; ++t) {
    float y0 = (v[2*t]   - mu) * inv * g[h*32 + 2*t]   + bb[h*32 + 2*t];
    float y1 = (v[2*t+1] - mu) * inv * g[h*32 + 2*t+1] + bb[h*32 + 2*t+1];
    r[t] = (unsigned)f2bf(y0) | ((unsigned)f2bf(y1) << 16);
  }
  unsigned short* o = qout + (size_t)idx * 32;
#pragma unroll
  for (int t4 = 0; t4 < 4; ++t4) {
    uint4 pk = {r[t4*4], r[t4*4+1], r[t4*4+2], r[t4*4+3]};
    *(uint4*)(o + t4 * 8) = pk;
  }
}

// ---------------- k: heads + LN -> bf16 [bh,256,32]; v -> bf16 fragment layout ---------
__global__ __launch_bounds__(256) void kvln_kernel(
    const float* __restrict__ ksr, const float* __restrict__ vsr,
    const float* __restrict__ g, const float* __restrict__ bb,
    unsigned short* __restrict__ kln, unsigned short* __restrict__ vfrag) {
  int idx = blockIdx.x * 256 + threadIdx.x;   // (b*8+h)*256 + j
  int j = idx & 255;
  int bh = idx >> 8;
  int h = bh & 7, b = bh >> 3;
  const float* kb = ksr + ((size_t)b * 256 + h) * 256 + j;   // channel d*8+h
  const float* vb = vsr + ((size_t)b * 256 + h) * 256 + j;
  float v[32];
  float mu = 0.f;
#pragma unroll
  for (int d = 0; d < 32; ++d) { v[d] = kb[d * 2048]; mu += v[d]; }
  mu *= (1.f / 32.f);
  float var = 0.f;
#pragma unroll
  for (int d = 0; d < 32; ++d) { float t = v[d] - mu; var += t * t; }
  var *= (1.f / 32.f);
  float inv = 1.0f / sqrtf(var + 1e-6f);
  unsigned r[16];
#pragma unroll
  for (int t = 0; t < 16; ++t) {
    float y0 = (v[2*t]   - mu) * inv * g[h*32 + 2*t]   + bb[h*32 + 2*t];
    float y1 = (v[2*t+1] - mu) * inv * g[h*32 + 2*t+1] + bb[h*32 + 2*t+1];
    r[t] = (unsigned)f2bf(y0) | ((unsigned)f2bf(y1) << 16);
  }
  unsigned short* ko = kln + (size_t)idx * 32;
#pragma unroll
  for (int t4 = 0; t4 < 4; ++t4) {
    uint4 pk = {r[t4*4], r[t4*4+1], r[t4*4+2], r[t4*4+3]};
    *(uint4*)(ko + t4 * 8) = pk;
  }
  // V in 16x16x16 A-fragment layout
  int c = j >> 4, gq = (j >> 2) & 3, ii = j & 3;
  unsigned short* vo = vfrag + (size_t)bh * 32 * 256;
#pragma unroll
  for (int d = 0; d < 32; ++d) {
    int dt = d >> 4, dr = d & 15;
    vo[(c * 2 + dt) * 256 + (gq * 16 + dr) * 4 + ii] = f2bf(vb[d * 2048]);
  }
}

// ---------------- bias_pre[h][g][j] = btab[relidx[g*256+j]*8+h] / 32 ----------------
__global__ __launch_bounds__(256) void biaspre_kernel(
    const float* __restrict__ btab, const int* __restrict__ relidx,
    float* __restrict__ bias_pre) {
  int idx = blockIdx.x * 256 + threadIdx.x;   // h*65536 + g*256 + j
  int j = idx & 255, g = (idx >> 8) & 255, h = idx >> 16;
  bias_pre[idx] = btab[relidx[g * 256 + j] * 8 + h] * 0.03125f;
}

// ---------------- MFMA attention (unchanged from round 2) ----------------
__global__ __launch_bounds__(256) void attn_mfma_kernel(
    const unsigned short* __restrict__ qln, const unsigned short* __restrict__ kln,
    const unsigned short* __restrict__ vfrag, const float* __restrict__ bias_pre,
    float* __restrict__ attn_out, float* __restrict__ out_nchw) {
  int tile = blockIdx.x, h = blockIdx.y, b = blockIdx.z;
  int bh = b * 8 + h;
  int tid = threadIdx.x;
  int w = tid >> 6, l = tid & 63;
  int lr = l & 15, lg = l >> 4;
  int qbase = tile * 64 + w * 16;
  int q = qbase + lr;
  int iy = q >> 6, ix = q & 63;
  int g = (iy >> 2) * 16 + (ix >> 2);

  bf16x8 qf = *(const bf16x8*)(qln + ((size_t)bh * 4096 + q) * 32 + lg * 8);

  const unsigned short* kbase = kln + (size_t)bh * 256 * 32 + lr * 32 + lg * 8;
  const unsigned short* vbase = vfrag + (size_t)bh * 32 * 256 + l * 4;
  const float* bbase = bias_pre + ((size_t)h * 256 + g) * 256 + lg * 4;
  float* abase = attn_out + ((size_t)bh * 4096 + q) * 256 + lg * 4;

  f32x4 z = {0.f, 0.f, 0.f, 0.f};
  f32x4 oacc0 = z, oacc1 = z;
#pragma unroll
  for (int c = 0; c < 16; ++c) {
    bf16x8 kf = *(const bf16x8*)(kbase + c * 16 * 32);
    f32x4 s = __builtin_amdgcn_mfma_f32_16x16x32_bf16(kf, qf, z, 0, 0, 0);
    f32x4 bias = *(const f32x4*)(bbase + c * 16);
    f32x4 t = s * 0.03125f + bias;
    *(f32x4*)(abase + c * 16) = t;
    bf16x4 pb;
    pb[0] = (short)f2bf(t.x);
    pb[1] = (short)f2bf(t.y);
    pb[2] = (short)f2bf(t.z);
    pb[3] = (short)f2bf(t.w);
    bf16x4 va0 = *(const bf16x4*)(vbase + (c * 2 + 0) * 256);
    bf16x4 va1 = *(const bf16x4*)(vbase + (c * 2 + 1) * 256);
    oacc0 = __builtin_amdgcn_mfma_f32_16x16x16bf16_1k(va0, pb, oacc0, 0, 0, 0);
    oacc1 = __builtin_amdgcn_mfma_f32_16x16x16bf16_1k(va1, pb, oacc1, 0, 0, 0);
  }
  float ov[8] = {oacc0.x, oacc0.y, oacc0.z, oacc0.w,
                 oacc1.x, oacc1.y, oacc1.z, oacc1.w};
#pragma unroll
  for (int dt = 0; dt < 2; ++dt) {
#pragma unroll
    for (int r = 0; r < 4; ++r) {
      int d = dt * 16 + lg * 4 + r;
      int cc = d * 8 + h;
      out_nchw[((size_t)b * 256 + cc) * HW_ + qbase + lr] = ov[dt * 4 + r];
    }
  }
}

extern "C" void kernel_launch(void* const* d_in, const int* in_sizes, int n_in,
                              void* d_out, int out_size, void* d_ws, size_t ws_size,
                              hipStream_t stream) {
  const float* x      = (const float*)d_in[0];
  const float* qkv_dw = (const float*)d_in[1];
  const float* qkv_pw = (const float*)d_in[2];
  const float* out_dw = (const float*)d_in[3];
  const float* out_pw = (const float*)d_in[4];
  const float* gq     = (const float*)d_in[5];
  const float* bq     = (const float*)d_in[6];
  const float* gk     = (const float*)d_in[7];
  const float* bk     = (const float*)d_in[8];
  const float* btab   = (const float*)d_in[9];
  const int*   relidx = (const int*)d_in[10];

  float* out  = (float*)d_out;            // 8,388,608 floats
  float* attn = out + 8388608;            // 67,108,864 floats (268 MB)

  // qkv (100 MB fp32) lives in the dead prefix of the attn region; attn_mfma
  // overwrites it only after bilinear/qln consumed it.
  float* qkv = attn;
  unsigned short* qlnb = (unsigned short*)out;   // out region dead until pwconv2

  float* ws = (float*)d_ws;
  unsigned short* xT1 = (unsigned short*)ws;      // 8,388,608 ushorts
  unsigned short* xT2 = xT1 + 8388608;            // 8,388,608 ushorts
  float* onchw    = ws + 8388608;                 // 8,388,608 floats
  float* ksr      = ws + 16777216;                // 524,288
  float* vsr      = ksr + 524288;
  float* bias_pre = vsr + 524288;
  unsigned short* kln   = (unsigned short*)(bias_pre + 524288);  // 524,288
  unsigned short* vfrag = kln + 524288;                          // 524,288
  unsigned short* wbuf  = vfrag + 524288;                        // 262,144

  wcvt_kernel<<<1024, 256, 0, stream>>>(qkv_pw, out_pw, wbuf);
  dwconv_t_kernel<<<dim3(64, 4, 8), 256, 0, stream>>>(x, qkv_dw, xT1);
  pwconv_mfma_kernel<<<dim3(32, 6, 8), 256, 0, stream>>>(xT1, wbuf, qkv, 768);
  bilinear_kernel<<<4096, 256, 0, stream>>>(qkv, ksr, vsr);
  qln_kernel<<<1024, 256, 0, stream>>>(qkv, gq, bq, qlnb);
  kvln_kernel<<<64, 256, 0, stream>>>(ksr, vsr, gk, bk, kln, vfrag);
  biaspre_kernel<<<2048, 256, 0, stream>>>(btab, relidx, bias_pre);
  attn_mfma_kernel<<<dim3(64, 8, 8), 256, 0, stream>>>(qlnb, kln, vfrag, bias_pre,
                                                       attn, onchw);
  dwconv_t_kernel<<<dim3(64, 4, 8), 256, 0, stream>>>(onchw, out_dw, xT2);
  pwconv_mfma_kernel<<<dim3(32, 2, 8), 256, 0, stream>>>(xT2, wbuf + 196608, out, 256);
}

// Round 4
// 216.888 us; speedup vs baseline: 9.4663x; 1.1479x over previous
//
#include <hip/hip_runtime.h>
#include <cstdint>

#define HW_ 4096

typedef __attribute__((ext_vector_type(8))) short bf16x8;
typedef __attribute__((ext_vector_type(4))) short bf16x4;
typedef __attribute__((ext_vector_type(4))) float f32x4;

static __device__ __forceinline__ unsigned short f2bf(float f) {
  unsigned u = __builtin_bit_cast(unsigned, f);
  u += 0x7FFF + ((u >> 16) & 1);
  return (unsigned short)(u >> 16);
}
static __device__ __forceinline__ float bf2f(unsigned short u) {
  return __builtin_bit_cast(float, (unsigned)u << 16);
}
static __device__ __forceinline__ float ldf(const float* p) { return *p; }
static __device__ __forceinline__ float ldf(const unsigned short* p) { return bf2f(*p); }

static __device__ __forceinline__ void gl_lds16(const unsigned short* g,
                                                unsigned short* s) {
  __builtin_amdgcn_global_load_lds(
      (const __attribute__((address_space(1))) unsigned int*)g,
      (__attribute__((address_space(3))) unsigned int*)s, 16, 0, 0);
}

// ---------- prep: weights fp32->bf16 (768x256 then 256x256) + bias_pre ----------
__global__ __launch_bounds__(256) void prep_kernel(
    const float* __restrict__ pw1, const float* __restrict__ pw2,
    unsigned short* __restrict__ wb, const float* __restrict__ btab,
    const int* __restrict__ relidx, float* __restrict__ bias_pre) {
  int idx = blockIdx.x * 256 + threadIdx.x;   // 786432
  if (idx < 262144) {
    wb[idx] = f2bf(idx < 196608 ? pw1[idx] : pw2[idx - 196608]);
  } else {
    int t = idx - 262144;                     // h*65536 + g*256 + j
    int j = t & 255, g = (t >> 8) & 255, h = t >> 16;
    bias_pre[t] = btab[relidx[g * 256 + j] * 8 + h] * 0.03125f;
  }
}

// ---------- fused depthwise 3x3 (pad1) + bf16 + transpose -> XT[b][p][c] ----------
template <typename T>
__global__ __launch_bounds__(256) void dwconv_t_kernel(
    const T* __restrict__ x, const float* __restrict__ w9,
    unsigned short* __restrict__ xT) {
  __shared__ unsigned short lds_t[64][66];
  int iy = blockIdx.x;
  int cg = blockIdx.y;
  int b  = blockIdx.z;
  int tid = threadIdx.x;
  int px  = tid & 63;
  int cl0 = (tid >> 6) * 16;
  for (int e = 0; e < 16; ++e) {
    int c = cg * 64 + cl0 + e;
    const T* xp = x + ((size_t)b * 256 + c) * HW_;
    const float* wp = w9 + c * 9;
    float acc = 0.f;
#pragma unroll
    for (int dy = -1; dy <= 1; ++dy) {
      int yy = iy + dy;
      if (yy < 0 || yy > 63) continue;
#pragma unroll
      for (int dx = -1; dx <= 1; ++dx) {
        int xx = px + dx;
        if (xx < 0 || xx > 63) continue;
        acc += ldf(xp + yy * 64 + xx) * wp[(dy + 1) * 3 + dx + 1];
      }
    }
    lds_t[cl0 + e][px] = f2bf(acc);
  }
  __syncthreads();
#pragma unroll
  for (int j = 0; j < 2; ++j) {
    int flat = tid + j * 256;
    int rpx = flat >> 3, cseg = flat & 7;
    unsigned v0 = (unsigned)lds_t[cseg*8+0][rpx] | ((unsigned)lds_t[cseg*8+1][rpx] << 16);
    unsigned v1 = (unsigned)lds_t[cseg*8+2][rpx] | ((unsigned)lds_t[cseg*8+3][rpx] << 16);
    unsigned v2 = (unsigned)lds_t[cseg*8+4][rpx] | ((unsigned)lds_t[cseg*8+5][rpx] << 16);
    unsigned v3 = (unsigned)lds_t[cseg*8+6][rpx] | ((unsigned)lds_t[cseg*8+7][rpx] << 16);
    uint4 pk = {v0, v1, v2, v3};
    *(uint4*)(xT + ((size_t)b * 4096 + iy * 64 + rpx) * 256 + cg * 64 + cseg * 8) = pk;
  }
}

// ---------- pointwise conv as bf16 MFMA GEMM; output fp32 or bf16 ----------
template <int OUT_BF16>
__global__ __launch_bounds__(256) void pwconv_mfma_kernel(
    const unsigned short* __restrict__ XT, const unsigned short* __restrict__ W,
    void* __restrict__ Yv, int OC) {
  __shared__ unsigned short As[128 * 64];
  __shared__ unsigned short Bs[128 * 64];
  int b = blockIdx.z, oc0 = blockIdx.y * 128, p0 = blockIdx.x * 128;
  int tid = threadIdx.x;
  int w = tid >> 6, l = tid & 63;
  int wm = w >> 1, wn = w & 1;
  int lr = l & 15, lg = l >> 4;
  const unsigned short* Wp = W + (size_t)oc0 * 256;
  const unsigned short* Xp = XT + ((size_t)b * 4096 + p0) * 256;
  f32x4 acc[4][4] = {};
  for (int kt = 0; kt < 4; ++kt) {
    int k0 = kt * 64;
#pragma unroll
    for (int j = 0; j < 4; ++j) {
      int chunk = w * 4 + j;            // wave-uniform
      int row = chunk * 8 + (l >> 3);
      int lcu = (l & 7) ^ (row & 7);    // inverse-swizzled source column
      gl_lds16(Wp + (size_t)row * 256 + k0 + lcu * 8, &As[chunk * 512]);
      gl_lds16(Xp + (size_t)row * 256 + k0 + lcu * 8, &Bs[chunk * 512]);
    }
    __syncthreads();
#pragma unroll
    for (int ks = 0; ks < 2; ++ks) {
      bf16x8 af[4], bfr[4];
      int ku = ks * 4 + lg;
#pragma unroll
      for (int mi = 0; mi < 4; ++mi) {
        int row = wm * 64 + mi * 16 + lr;
        af[mi] = *(const bf16x8*)&As[row * 64 + (ku ^ (row & 7)) * 8];
      }
#pragma unroll
      for (int ni = 0; ni < 4; ++ni) {
        int row = wn * 64 + ni * 16 + lr;
        bfr[ni] = *(const bf16x8*)&Bs[row * 64 + (ku ^ (row & 7)) * 8];
      }
#pragma unroll
      for (int mi = 0; mi < 4; ++mi)
#pragma unroll
        for (int ni = 0; ni < 4; ++ni)
          acc[mi][ni] = __builtin_amdgcn_mfma_f32_16x16x32_bf16(
              af[mi], bfr[ni], acc[mi][ni], 0, 0, 0);
    }
    __syncthreads();
  }
  // D: col(l&15) = p-local (B rows), row((l>>4)*4+reg) = oc-local (A rows)
#pragma unroll
  for (int mi = 0; mi < 4; ++mi)
#pragma unroll
    for (int ni = 0; ni < 4; ++ni)
#pragma unroll
      for (int r = 0; r < 4; ++r) {
        int oc = oc0 + wm * 64 + mi * 16 + lg * 4 + r;
        int p  = p0 + wn * 64 + ni * 16 + lr;
        if constexpr (OUT_BF16) {
          ((unsigned short*)Yv)[((size_t)b * OC + oc) * HW_ + p] =
              f2bf(acc[mi][ni][r]);
        } else {
          ((float*)Yv)[((size_t)b * OC + oc) * HW_ + p] = acc[mi][ni][r];
        }
      }
}

// ---------- fused bilinear(64->16, align_corners) + heads + LN(k) -> kln, vfrag ----------
__global__ __launch_bounds__(256) void bilin_kvln_kernel(
    const unsigned short* __restrict__ qkvb, const float* __restrict__ g,
    const float* __restrict__ bb, unsigned short* __restrict__ kln,
    unsigned short* __restrict__ vfrag) {
  int idx = blockIdx.x * 256 + threadIdx.x;   // (b*8+h)*256 + j  (16384)
  int j = idx & 255;
  int bh = idx >> 8;
  int h = bh & 7, b = bh >> 3;
  int oy = j >> 4, ox = j & 15;
  const float s = 63.0f / 15.0f;
  float ys = oy * s, xf = ox * s;
  int y0 = (int)ys, x0 = (int)xf;
  int y1 = min(y0 + 1, 63), x1 = min(x0 + 1, 63);
  float wy = ys - (float)y0, wx = xf - (float)x0;
  float kv[32], vv[32];
  float mu = 0.f;
#pragma unroll
  for (int d = 0; d < 32; ++d) {
    const unsigned short* kp = qkvb + ((size_t)b * 768 + 256 + d * 8 + h) * HW_;
    const unsigned short* vp = qkvb + ((size_t)b * 768 + 512 + d * 8 + h) * HW_;
    float k00 = bf2f(kp[y0*64+x0]), k01 = bf2f(kp[y0*64+x1]);
    float k10 = bf2f(kp[y1*64+x0]), k11 = bf2f(kp[y1*64+x1]);
    float ktop = k00 * (1.f - wx) + k01 * wx;
    float kbot = k10 * (1.f - wx) + k11 * wx;
    kv[d] = ktop * (1.f - wy) + kbot * wy;
    float v00 = bf2f(vp[y0*64+x0]), v01 = bf2f(vp[y0*64+x1]);
    float v10 = bf2f(vp[y1*64+x0]), v11 = bf2f(vp[y1*64+x1]);
    float vtop = v00 * (1.f - wx) + v01 * wx;
    float vbot = v10 * (1.f - wx) + v11 * wx;
    vv[d] = vtop * (1.f - wy) + vbot * wy;
    mu += kv[d];
  }
  mu *= (1.f / 32.f);
  float var = 0.f;
#pragma unroll
  for (int d = 0; d < 32; ++d) { float t = kv[d] - mu; var += t * t; }
  var *= (1.f / 32.f);
  float inv = 1.0f / sqrtf(var + 1e-6f);
  unsigned r[16];
#pragma unroll
  for (int t = 0; t < 16; ++t) {
    float y0f = (kv[2*t]   - mu) * inv * g[h*32 + 2*t]   + bb[h*32 + 2*t];
    float y1f = (kv[2*t+1] - mu) * inv * g[h*32 + 2*t+1] + bb[h*32 + 2*t+1];
    r[t] = (unsigned)f2bf(y0f) | ((unsigned)f2bf(y1f) << 16);
  }
  unsigned short* ko = kln + (size_t)idx * 32;
#pragma unroll
  for (int t4 = 0; t4 < 4; ++t4) {
    uint4 pk = {r[t4*4], r[t4*4+1], r[t4*4+2], r[t4*4+3]};
    *(uint4*)(ko + t4 * 8) = pk;
  }
  // V in 16x16x16 A-fragment layout
  int c = j >> 4, gq = (j >> 2) & 3, ii = j & 3;
  unsigned short* vo = vfrag + (size_t)bh * 32 * 256;
#pragma unroll
  for (int d = 0; d < 32; ++d) {
    int dt = d >> 4, dr = d & 15;
    vo[(c * 2 + dt) * 256 + (gq * 16 + dr) * 4 + ii] = f2bf(vv[d]);
  }
}

// ---------------- q: gather heads + LayerNorm -> bf16 [B,8,4096,32] ----------------
__global__ __launch_bounds__(256) void qln_kernel(
    const unsigned short* __restrict__ qkvb, const float* __restrict__ g,
    const float* __restrict__ bb, unsigned short* __restrict__ qout) {
  int idx = blockIdx.x * 256 + threadIdx.x;   // (b*8+h)*4096 + i
  int i = idx & 4095;
  int bh = idx >> 12;
  int h = bh & 7, b = bh >> 3;
  const unsigned short* base = qkvb + ((size_t)b * 768 + h) * HW_ + i;
  float v[32];
  float mu = 0.f;
#pragma unroll
  for (int d = 0; d < 32; ++d) { v[d] = bf2f(base[(size_t)d * 8 * HW_]); mu += v[d]; }
  mu *= (1.f / 32.f);
  float var = 0.f;
#pragma unroll
  for (int d = 0; d < 32; ++d) { float t = v[d] - mu; var += t * t; }
  var *= (1.f / 32.f);
  float inv = 1.0f / sqrtf(var + 1e-6f);
  unsigned r[16];
#pragma unroll
  for (int t = 0; t < 16; ++t) {
    float y0 = (v[2*t]   - mu) * inv * g[h*32 + 2*t]   + bb[h*32 + 2*t];
    float y1 = (v[2*t+1] - mu) * inv * g[h*32 + 2*t+1] + bb[h*32 + 2*t+1];
    r[t] = (unsigned)f2bf(y0) | ((unsigned)f2bf(y1) << 16);
  }
  unsigned short* o = qout + (size_t)idx * 32;
#pragma unroll
  for (int t4 = 0; t4 < 4; ++t4) {
    uint4 pk = {r[t4*4], r[t4*4+1], r[t4*4+2], r[t4*4+3]};
    *(uint4*)(o + t4 * 8) = pk;
  }
}

// ---------------- MFMA attention; attn store nontemporal, spatial out bf16 ----------------
__global__ __launch_bounds__(256) void attn_mfma_kernel(
    const unsigned short* __restrict__ qln, const unsigned short* __restrict__ kln,
    const unsigned short* __restrict__ vfrag, const float* __restrict__ bias_pre,
    float* __restrict__ attn_out, unsigned short* __restrict__ out_nchw) {
  int tile = blockIdx.x, h = blockIdx.y, b = blockIdx.z;
  int bh = b * 8 + h;
  int tid = threadIdx.x;
  int w = tid >> 6, l = tid & 63;
  int lr = l & 15, lg = l >> 4;
  int qbase = tile * 64 + w * 16;
  int q = qbase + lr;
  int iy = q >> 6, ix = q & 63;
  int g = (iy >> 2) * 16 + (ix >> 2);

  bf16x8 qf = *(const bf16x8*)(qln + ((size_t)bh * 4096 + q) * 32 + lg * 8);

  const unsigned short* kbase = kln + (size_t)bh * 256 * 32 + lr * 32 + lg * 8;
  const unsigned short* vbase = vfrag + (size_t)bh * 32 * 256 + l * 4;
  const float* bbase = bias_pre + ((size_t)h * 256 + g) * 256 + lg * 4;
  float* abase = attn_out + ((size_t)bh * 4096 + q) * 256 + lg * 4;

  f32x4 z = {0.f, 0.f, 0.f, 0.f};
  f32x4 oacc0 = z, oacc1 = z;
#pragma unroll
  for (int c = 0; c < 16; ++c) {
    bf16x8 kf = *(const bf16x8*)(kbase + c * 16 * 32);
    f32x4 s = __builtin_amdgcn_mfma_f32_16x16x32_bf16(kf, qf, z, 0, 0, 0);
    f32x4 bias = *(const f32x4*)(bbase + c * 16);
    f32x4 t = s * 0.03125f + bias;
    __builtin_nontemporal_store(t, (f32x4*)(abase + c * 16));
    bf16x4 pb;
    pb[0] = (short)f2bf(t.x);
    pb[1] = (short)f2bf(t.y);
    pb[2] = (short)f2bf(t.z);
    pb[3] = (short)f2bf(t.w);
    bf16x4 va0 = *(const bf16x4*)(vbase + (c * 2 + 0) * 256);
    bf16x4 va1 = *(const bf16x4*)(vbase + (c * 2 + 1) * 256);
    oacc0 = __builtin_amdgcn_mfma_f32_16x16x16bf16_1k(va0, pb, oacc0, 0, 0, 0);
    oacc1 = __builtin_amdgcn_mfma_f32_16x16x16bf16_1k(va1, pb, oacc1, 0, 0, 0);
  }
  float ov[8] = {oacc0.x, oacc0.y, oacc0.z, oacc0.w,
                 oacc1.x, oacc1.y, oacc1.z, oacc1.w};
#pragma unroll
  for (int dt = 0; dt < 2; ++dt) {
#pragma unroll
    for (int r = 0; r < 4; ++r) {
      int d = dt * 16 + lg * 4 + r;
      int cc = d * 8 + h;
      out_nchw[((size_t)b * 256 + cc) * HW_ + qbase + lr] = f2bf(ov[dt * 4 + r]);
    }
  }
}

extern "C" void kernel_launch(void* const* d_in, const int* in_sizes, int n_in,
                              void* d_out, int out_size, void* d_ws, size_t ws_size,
                              hipStream_t stream) {
  const float* x      = (const float*)d_in[0];
  const float* qkv_dw = (const float*)d_in[1];
  const float* qkv_pw = (const float*)d_in[2];
  const float* out_dw = (const float*)d_in[3];
  const float* out_pw = (const float*)d_in[4];
  const float* gq     = (const float*)d_in[5];
  const float* bq     = (const float*)d_in[6];
  const float* gk     = (const float*)d_in[7];
  const float* bk     = (const float*)d_in[8];
  const float* btab   = (const float*)d_in[9];
  const int*   relidx = (const int*)d_in[10];

  float* out  = (float*)d_out;            // 8,388,608 floats
  float* attn = out + 8388608;            // 67,108,864 floats (268 MB)

  // bf16 qkv lives in the dead prefix of the attn region (50 MB <= 268 MB);
  // attn_mfma overwrites it only after bilin_kvln/qln consumed it.
  unsigned short* qkvb = (unsigned short*)attn;
  unsigned short* qlnb = (unsigned short*)out;   // out region dead until pwconv2

  float* ws = (float*)d_ws;
  unsigned short* xT1    = (unsigned short*)ws;            // 8,388,608 u16
  unsigned short* xT2    = xT1 + 8388608;                  // 8,388,608 u16
  unsigned short* onchwb = xT2 + 8388608;                  // 8,388,608 u16
  unsigned short* kln    = onchwb + 8388608;               // 524,288 u16
  unsigned short* vfrag  = kln + 524288;                   // 524,288 u16
  unsigned short* wbuf   = vfrag + 524288;                 // 262,144 u16
  float* bias_pre = (float*)(wbuf + 262144);               // 524,288 f32

  prep_kernel<<<3072, 256, 0, stream>>>(qkv_pw, out_pw, wbuf, btab, relidx, bias_pre);
  dwconv_t_kernel<float><<<dim3(64, 4, 8), 256, 0, stream>>>(x, qkv_dw, xT1);
  pwconv_mfma_kernel<1><<<dim3(32, 6, 8), 256, 0, stream>>>(xT1, wbuf, qkvb, 768);
  bilin_kvln_kernel<<<64, 256, 0, stream>>>(qkvb, gk, bk, kln, vfrag);
  qln_kernel<<<1024, 256, 0, stream>>>(qkvb, gq, bq, qlnb);
  attn_mfma_kernel<<<dim3(64, 8, 8), 256, 0, stream>>>(qlnb, kln, vfrag, bias_pre,
                                                       attn, onchwb);
  dwconv_t_kernel<unsigned short><<<dim3(64, 4, 8), 256, 0, stream>>>(onchwb, out_dw, xT2);
  pwconv_mfma_kernel<0><<<dim3(32, 2, 8), 256, 0, stream>>>(xT2, wbuf + 196608, out, 256);
}

// Round 5
// 204.081 us; speedup vs baseline: 10.0604x; 1.0628x over previous
//
#include <hip/hip_runtime.h>
#include <cstdint>

#define HW_ 4096

typedef __attribute__((ext_vector_type(8))) short bf16x8;
typedef __attribute__((ext_vector_type(4))) short bf16x4;
typedef __attribute__((ext_vector_type(4))) float f32x4;

static __device__ __forceinline__ unsigned short f2bf(float f) {
  unsigned u = __builtin_bit_cast(unsigned, f);
  u += 0x7FFF + ((u >> 16) & 1);
  return (unsigned short)(u >> 16);
}
static __device__ __forceinline__ float bf2f(unsigned short u) {
  return __builtin_bit_cast(float, (unsigned)u << 16);
}
static __device__ __forceinline__ float ldf(const float* p) { return *p; }
static __device__ __forceinline__ float ldf(const unsigned short* p) { return bf2f(*p); }

static __device__ __forceinline__ void gl_lds16(const unsigned short* g,
                                                unsigned short* s) {
  __builtin_amdgcn_global_load_lds(
      (const __attribute__((address_space(1))) unsigned int*)g,
      (__attribute__((address_space(3))) unsigned int*)s, 16, 0, 0);
}

// ---------- prep: weights fp32->bf16 (768x256 then 256x256) + bias_pre ----------
__global__ __launch_bounds__(256) void prep_kernel(
    const float* __restrict__ pw1, const float* __restrict__ pw2,
    unsigned short* __restrict__ wb, const float* __restrict__ btab,
    const int* __restrict__ relidx, float* __restrict__ bias_pre) {
  int idx = blockIdx.x * 256 + threadIdx.x;   // 786432
  if (idx < 262144) {
    wb[idx] = f2bf(idx < 196608 ? pw1[idx] : pw2[idx - 196608]);
  } else {
    int t = idx - 262144;                     // h*65536 + g*256 + j
    int j = t & 255, g = (t >> 8) & 255, h = t >> 16;
    bias_pre[t] = btab[relidx[g * 256 + j] * 8 + h] * 0.03125f;
  }
}

// ---------- fused depthwise 3x3 (pad1) + bf16 + transpose -> XT[b][p][c] ----------
template <typename T>
__global__ __launch_bounds__(256) void dwconv_t_kernel(
    const T* __restrict__ x, const float* __restrict__ w9,
    unsigned short* __restrict__ xT) {
  __shared__ unsigned short lds_t[64][66];
  int iy = blockIdx.x;
  int cg = blockIdx.y;
  int b  = blockIdx.z;
  int tid = threadIdx.x;
  int px  = tid & 63;
  int cl0 = (tid >> 6) * 16;
  for (int e = 0; e < 16; ++e) {
    int c = cg * 64 + cl0 + e;
    const T* xp = x + ((size_t)b * 256 + c) * HW_;
    const float* wp = w9 + c * 9;
    float acc = 0.f;
#pragma unroll
    for (int dy = -1; dy <= 1; ++dy) {
      int yy = iy + dy;
      if (yy < 0 || yy > 63) continue;
#pragma unroll
      for (int dx = -1; dx <= 1; ++dx) {
        int xx = px + dx;
        if (xx < 0 || xx > 63) continue;
        acc += ldf(xp + yy * 64 + xx) * wp[(dy + 1) * 3 + dx + 1];
      }
    }
    lds_t[cl0 + e][px] = f2bf(acc);
  }
  __syncthreads();
#pragma unroll
  for (int j = 0; j < 2; ++j) {
    int flat = tid + j * 256;
    int rpx = flat >> 3, cseg = flat & 7;
    unsigned v0 = (unsigned)lds_t[cseg*8+0][rpx] | ((unsigned)lds_t[cseg*8+1][rpx] << 16);
    unsigned v1 = (unsigned)lds_t[cseg*8+2][rpx] | ((unsigned)lds_t[cseg*8+3][rpx] << 16);
    unsigned v2 = (unsigned)lds_t[cseg*8+4][rpx] | ((unsigned)lds_t[cseg*8+5][rpx] << 16);
    unsigned v3 = (unsigned)lds_t[cseg*8+6][rpx] | ((unsigned)lds_t[cseg*8+7][rpx] << 16);
    uint4 pk = {v0, v1, v2, v3};
    *(uint4*)(xT + ((size_t)b * 4096 + iy * 64 + rpx) * 256 + cg * 64 + cseg * 8) = pk;
  }
}

// ---------- pointwise conv as bf16 MFMA GEMM; bf16 out via LDS-staged store ----------
template <int OUT_BF16>
__global__ __launch_bounds__(256) void pwconv_mfma_kernel(
    const unsigned short* __restrict__ XT, const unsigned short* __restrict__ W,
    void* __restrict__ Yv, int OC) {
  __shared__ unsigned short As[128 * 64];
  __shared__ unsigned short Bs[128 * 64];
  int b = blockIdx.z, oc0 = blockIdx.y * 128, p0 = blockIdx.x * 128;
  int tid = threadIdx.x;
  int w = tid >> 6, l = tid & 63;
  int wm = w >> 1, wn = w & 1;
  int lr = l & 15, lg = l >> 4;
  const unsigned short* Wp = W + (size_t)oc0 * 256;
  const unsigned short* Xp = XT + ((size_t)b * 4096 + p0) * 256;
  f32x4 acc[4][4] = {};
  for (int kt = 0; kt < 4; ++kt) {
    int k0 = kt * 64;
#pragma unroll
    for (int j = 0; j < 4; ++j) {
      int chunk = w * 4 + j;            // wave-uniform
      int row = chunk * 8 + (l >> 3);
      int lcu = (l & 7) ^ (row & 7);    // inverse-swizzled source column
      gl_lds16(Wp + (size_t)row * 256 + k0 + lcu * 8, &As[chunk * 512]);
      gl_lds16(Xp + (size_t)row * 256 + k0 + lcu * 8, &Bs[chunk * 512]);
    }
    __syncthreads();
#pragma unroll
    for (int ks = 0; ks < 2; ++ks) {
      bf16x8 af[4], bfr[4];
      int ku = ks * 4 + lg;
#pragma unroll
      for (int mi = 0; mi < 4; ++mi) {
        int row = wm * 64 + mi * 16 + lr;
        af[mi] = *(const bf16x8*)&As[row * 64 + (ku ^ (row & 7)) * 8];
      }
#pragma unroll
      for (int ni = 0; ni < 4; ++ni) {
        int row = wn * 64 + ni * 16 + lr;
        bfr[ni] = *(const bf16x8*)&Bs[row * 64 + (ku ^ (row & 7)) * 8];
      }
#pragma unroll
      for (int mi = 0; mi < 4; ++mi)
#pragma unroll
        for (int ni = 0; ni < 4; ++ni)
          acc[mi][ni] = __builtin_amdgcn_mfma_f32_16x16x32_bf16(
              af[mi], bfr[ni], acc[mi][ni], 0, 0, 0);
    }
    __syncthreads();
  }
  // D: col(l&15) = p-local, row((l>>4)*4+reg) = oc-local
  if constexpr (OUT_BF16) {
    __shared__ unsigned short Cs[128][136];   // pad 136 -> 272B rows (16B aligned)
#pragma unroll
    for (int mi = 0; mi < 4; ++mi)
#pragma unroll
      for (int ni = 0; ni < 4; ++ni)
#pragma unroll
        for (int r = 0; r < 4; ++r)
          Cs[wm * 64 + mi * 16 + lg * 4 + r][wn * 64 + ni * 16 + lr] =
              f2bf(acc[mi][ni][r]);
    __syncthreads();
    unsigned short* Yb = (unsigned short*)Yv + (size_t)b * OC * HW_;
    int pc = tid & 15, ocr = tid >> 4;
#pragma unroll
    for (int it = 0; it < 8; ++it) {
      int oc = it * 16 + ocr;
      uint4 pk = *(const uint4*)&Cs[oc][pc * 8];
      *(uint4*)(Yb + (size_t)(oc0 + oc) * HW_ + p0 + pc * 8) = pk;
    }
  } else {
    float* Yb = (float*)Yv + (size_t)b * OC * HW_;
#pragma unroll
    for (int mi = 0; mi < 4; ++mi)
#pragma unroll
      for (int ni = 0; ni < 4; ++ni)
#pragma unroll
        for (int r = 0; r < 4; ++r) {
          int oc = oc0 + wm * 64 + mi * 16 + lg * 4 + r;
          int p  = p0 + wn * 64 + ni * 16 + lr;
          Yb[(size_t)oc * HW_ + p] = acc[mi][ni][r];
        }
  }
}

// ---------- fused bilinear(64->16,ac) + heads + LN(k) -> kln, vfrag ----------
// 256 blocks x 256 thr; thread = jloc*4 + dg, handles 8 d = dg*8..dg*8+7
__global__ __launch_bounds__(256) void bilin_kvln_kernel(
    const unsigned short* __restrict__ qkvb, const float* __restrict__ g,
    const float* __restrict__ bb, unsigned short* __restrict__ kln,
    unsigned short* __restrict__ vfrag) {
  int bx = blockIdx.x;
  int bh = bx >> 2, jt = bx & 3;
  int h = bh & 7, b = bh >> 3;
  int tid = threadIdx.x;
  int jloc = tid >> 2, dg = tid & 3;
  int j = jt * 64 + jloc;
  int oy = j >> 4, ox = j & 15;
  const float s = 63.0f / 15.0f;
  float ys = oy * s, xf = ox * s;
  int y0 = (int)ys, x0 = (int)xf;
  int y1 = min(y0 + 1, 63), x1 = min(x0 + 1, 63);
  float wy = ys - (float)y0, wx = xf - (float)x0;
  float kv[8], vv[8];
  float sum = 0.f, sum2 = 0.f;
#pragma unroll
  for (int e = 0; e < 8; ++e) {
    int d = dg * 8 + e;
    const unsigned short* kp = qkvb + ((size_t)b * 768 + 256 + d * 8 + h) * HW_;
    const unsigned short* vp = qkvb + ((size_t)b * 768 + 512 + d * 8 + h) * HW_;
    float k00 = bf2f(kp[y0*64+x0]), k01 = bf2f(kp[y0*64+x1]);
    float k10 = bf2f(kp[y1*64+x0]), k11 = bf2f(kp[y1*64+x1]);
    float ktop = k00 * (1.f - wx) + k01 * wx;
    float kbot = k10 * (1.f - wx) + k11 * wx;
    kv[e] = ktop * (1.f - wy) + kbot * wy;
    float v00 = bf2f(vp[y0*64+x0]), v01 = bf2f(vp[y0*64+x1]);
    float v10 = bf2f(vp[y1*64+x0]), v11 = bf2f(vp[y1*64+x1]);
    float vtop = v00 * (1.f - wx) + v01 * wx;
    float vbot = v10 * (1.f - wx) + v11 * wx;
    vv[e] = vtop * (1.f - wy) + vbot * wy;
    sum += kv[e]; sum2 += kv[e] * kv[e];
  }
  sum  += __shfl_xor(sum, 1, 64);  sum  += __shfl_xor(sum, 2, 64);
  sum2 += __shfl_xor(sum2, 1, 64); sum2 += __shfl_xor(sum2, 2, 64);
  float mu = sum * (1.f / 32.f);
  float var = sum2 * (1.f / 32.f) - mu * mu;
  float inv = 1.0f / sqrtf(var + 1e-6f);
  unsigned r[4];
#pragma unroll
  for (int t = 0; t < 4; ++t) {
    int d0 = dg * 8 + 2 * t;
    float y0f = (kv[2*t]   - mu) * inv * g[h*32 + d0]     + bb[h*32 + d0];
    float y1f = (kv[2*t+1] - mu) * inv * g[h*32 + d0 + 1] + bb[h*32 + d0 + 1];
    r[t] = (unsigned)f2bf(y0f) | ((unsigned)f2bf(y1f) << 16);
  }
  uint4 pk = {r[0], r[1], r[2], r[3]};
  *(uint4*)(kln + ((size_t)bh * 256 + j) * 32 + dg * 8) = pk;
  // V in 16x16x16 A-fragment layout
  int c = j >> 4, gq = (j >> 2) & 3, ii = j & 3;
  unsigned short* vo = vfrag + (size_t)bh * 32 * 256;
#pragma unroll
  for (int e = 0; e < 8; ++e) {
    int d = dg * 8 + e;
    int dt = d >> 4, dr = d & 15;
    vo[(c * 2 + dt) * 256 + (gq * 16 + dr) * 4 + ii] = f2bf(vv[e]);
  }
}

// ---------------- MFMA attention with fused q-LayerNorm ----------------
__global__ __launch_bounds__(256) void attn_mfma_kernel(
    const unsigned short* __restrict__ qkvb, const float* __restrict__ gq,
    const float* __restrict__ bq, const unsigned short* __restrict__ kln,
    const unsigned short* __restrict__ vfrag, const float* __restrict__ bias_pre,
    float* __restrict__ attn_out, unsigned short* __restrict__ out_nchw) {
  int tile = blockIdx.x, h = blockIdx.y, b = blockIdx.z;
  int bh = b * 8 + h;
  int tid = threadIdx.x;
  int w = tid >> 6, l = tid & 63;
  int lr = l & 15, lg = l >> 4;
  int qbase = tile * 64 + w * 16;
  int q = qbase + lr;
  int iy = q >> 6, ix = q & 63;
  int g = (iy >> 2) * 16 + (ix >> 2);

  // fused q LayerNorm: lane loads its 8 raw q values, reduce across lg via shfl
  const unsigned short* qp = qkvb + ((size_t)b * 768 + h) * HW_ + q;
  float qv[8];
  float sum = 0.f, sum2 = 0.f;
#pragma unroll
  for (int e = 0; e < 8; ++e) {
    qv[e] = bf2f(qp[(size_t)((lg * 8 + e) * 8) * HW_]);
    sum += qv[e]; sum2 += qv[e] * qv[e];
  }
  sum  += __shfl_xor(sum, 16, 64);  sum  += __shfl_xor(sum, 32, 64);
  sum2 += __shfl_xor(sum2, 16, 64); sum2 += __shfl_xor(sum2, 32, 64);
  float mu = sum * (1.f / 32.f);
  float var = sum2 * (1.f / 32.f) - mu * mu;
  float inv = 1.0f / sqrtf(var + 1e-6f);
  bf16x8 qf;
#pragma unroll
  for (int e = 0; e < 8; ++e) {
    int d = lg * 8 + e;
    float y = (qv[e] - mu) * inv * gq[h * 32 + d] + bq[h * 32 + d];
    qf[e] = (short)f2bf(y);
  }

  const unsigned short* kbase = kln + (size_t)bh * 256 * 32 + lr * 32 + lg * 8;
  const unsigned short* vbase = vfrag + (size_t)bh * 32 * 256 + l * 4;
  const float* bbase = bias_pre + ((size_t)h * 256 + g) * 256 + lg * 4;
  float* abase = attn_out + ((size_t)bh * 4096 + q) * 256 + lg * 4;

  f32x4 z = {0.f, 0.f, 0.f, 0.f};
  f32x4 oacc0 = z, oacc1 = z;
#pragma unroll
  for (int c = 0; c < 16; ++c) {
    bf16x8 kf = *(const bf16x8*)(kbase + c * 16 * 32);
    f32x4 s = __builtin_amdgcn_mfma_f32_16x16x32_bf16(kf, qf, z, 0, 0, 0);
    f32x4 bias = *(const f32x4*)(bbase + c * 16);
    f32x4 t = s * 0.03125f + bias;
    __builtin_nontemporal_store(t, (f32x4*)(abase + c * 16));
    bf16x4 pb;
    pb[0] = (short)f2bf(t.x);
    pb[1] = (short)f2bf(t.y);
    pb[2] = (short)f2bf(t.z);
    pb[3] = (short)f2bf(t.w);
    bf16x4 va0 = *(const bf16x4*)(vbase + (c * 2 + 0) * 256);
    bf16x4 va1 = *(const bf16x4*)(vbase + (c * 2 + 1) * 256);
    oacc0 = __builtin_amdgcn_mfma_f32_16x16x16bf16_1k(va0, pb, oacc0, 0, 0, 0);
    oacc1 = __builtin_amdgcn_mfma_f32_16x16x16bf16_1k(va1, pb, oacc1, 0, 0, 0);
  }
  float ov[8] = {oacc0.x, oacc0.y, oacc0.z, oacc0.w,
                 oacc1.x, oacc1.y, oacc1.z, oacc1.w};
#pragma unroll
  for (int dt = 0; dt < 2; ++dt) {
#pragma unroll
    for (int r = 0; r < 4; ++r) {
      int d = dt * 16 + lg * 4 + r;
      int cc = d * 8 + h;
      out_nchw[((size_t)b * 256 + cc) * HW_ + qbase + lr] = f2bf(ov[dt * 4 + r]);
    }
  }
}

extern "C" void kernel_launch(void* const* d_in, const int* in_sizes, int n_in,
                              void* d_out, int out_size, void* d_ws, size_t ws_size,
                              hipStream_t stream) {
  const float* x      = (const float*)d_in[0];
  const float* qkv_dw = (const float*)d_in[1];
  const float* qkv_pw = (const float*)d_in[2];
  const float* out_dw = (const float*)d_in[3];
  const float* out_pw = (const float*)d_in[4];
  const float* gq     = (const float*)d_in[5];
  const float* bq     = (const float*)d_in[6];
  const float* gk     = (const float*)d_in[7];
  const float* bk     = (const float*)d_in[8];
  const float* btab   = (const float*)d_in[9];
  const int*   relidx = (const int*)d_in[10];

  float* out  = (float*)d_out;            // 8,388,608 floats
  float* attn = out + 8388608;            // 67,108,864 floats (268 MB)

  unsigned short* us = (unsigned short*)d_ws;
  unsigned short* xT1    = us;                    // 16.8 MB
  unsigned short* xT2    = us + 8388608;          // 16.8 MB
  unsigned short* onchwb = us + 16777216;         // 16.8 MB
  unsigned short* kln    = us + 25165824;         // 1 MB
  unsigned short* vfrag  = us + 25690112;         // 1 MB
  unsigned short* wbuf   = us + 26214400;         // 0.5 MB
  float* bias_pre = (float*)(us + 26476544);      // 2 MB
  unsigned short* qkvb   = us + 27525120;         // 50 MB  (total ~105 MB)

  prep_kernel<<<3072, 256, 0, stream>>>(qkv_pw, out_pw, wbuf, btab, relidx, bias_pre);
  dwconv_t_kernel<float><<<dim3(64, 4, 8), 256, 0, stream>>>(x, qkv_dw, xT1);
  pwconv_mfma_kernel<1><<<dim3(32, 6, 8), 256, 0, stream>>>(xT1, wbuf, qkvb, 768);
  bilin_kvln_kernel<<<256, 256, 0, stream>>>(qkvb, gk, bk, kln, vfrag);
  attn_mfma_kernel<<<dim3(64, 8, 8), 256, 0, stream>>>(qkvb, gq, bq, kln, vfrag,
                                                       bias_pre, attn, onchwb);
  dwconv_t_kernel<unsigned short><<<dim3(64, 4, 8), 256, 0, stream>>>(onchwb, out_dw, xT2);
  pwconv_mfma_kernel<0><<<dim3(32, 2, 8), 256, 0, stream>>>(xT2, wbuf + 196608, out, 256);
}